// Round 2
// baseline (1087.511 us; speedup 1.0000x reference)
//
#include <hip/hip_runtime.h>
#include <hip/hip_bf16.h>

typedef __bf16 bf16x8 __attribute__((ext_vector_type(8)));
typedef float f32x4 __attribute__((ext_vector_type(4)));

__device__ __forceinline__ unsigned short f2bf(float x) {
  union { float f; unsigned int u; } v; v.f = x;
  unsigned int r = (v.u + 0x7FFFu + ((v.u >> 16) & 1u)) >> 16;
  return (unsigned short)r;
}
__device__ __forceinline__ float bf2f(unsigned int u16) {
  union { unsigned int u; float f; } v; v.u = u16 << 16;
  return v.f;
}

// feats [N][16] f32 -> [N+1][32] bf16 (upper 16 cols and row N stay zero via memset)
__global__ void cvt_feats_kernel(const float* __restrict__ f, unsigned short* __restrict__ fb, int n16) {
  int t = blockIdx.x * 256 + threadIdx.x;
  if (t >= n16) return;
  int i = t >> 4, j = t & 15;
  fb[(size_t)i * 32 + j] = f2bf(f[t]);
}

// Pack W[k][CI][CO] f32 into MFMA B-fragment order:
// Wp[(((k*NT+nt)*KK+kk)*64 + l)*8 + j] = bf16(W[k][kk*32 + (l>>4)*8 + j][nt*16 + (l&15)]), 0 if kg>=CI
__global__ void pack_w_kernel(const float* __restrict__ W, unsigned short* __restrict__ Wp,
                              int CI, int CO, int NT, int KK) {
  int t = blockIdx.x * 256 + threadIdx.x;
  int total = 27 * NT * KK * 512;
  if (t >= total) return;
  int j = t & 7, l = (t >> 3) & 63;
  int g = t >> 9;
  int kk = g % KK; g /= KK;
  int nt = g % NT; int k = g / NT;
  int kg = kk * 32 + ((l >> 4) * 8) + j;
  int c = nt * 16 + (l & 15);
  float v = (kg < CI) ? W[((size_t)k * CI + kg) * CO + c] : 0.0f;
  Wp[t] = f2bf(v);
}

// tab[k][o] = -1 for o < n (cheaper than memsetting the full n_cap-sized buffer)
__global__ void fill_tab_kernel(int* __restrict__ tab, int maxo,
                                const int* __restrict__ n_ptr, int n_cap) {
  int n = n_cap;
  if (n_ptr) { int nv = n_ptr[0]; if (nv < n) n = nv; }
  int o = blockIdx.x * 256 + threadIdx.x;
  if (o >= n) return;
  tab[(size_t)blockIdx.y * maxo + o] = -1;
}

// tab[k][o] = input index (scatter from pair lists; unique per (k,o) by construction)
__global__ void build_table_kernel(const int* __restrict__ pin, const int* __restrict__ pout,
                                   int P, int maxo, int* __restrict__ tab,
                                   const int* __restrict__ n_ptr, int n_cap) {
  int p = blockIdx.x * 256 + threadIdx.x;
  if (p >= P) return;
  int k = blockIdx.y;
  int n = n_cap;
  if (n_ptr) { int nv = n_ptr[0]; if (nv < n) n = nv; }
  size_t e = (size_t)k * P + p;
  int o = pout[e];
  if (o < n) tab[(size_t)k * maxo + o] = pin[e];
}

// One wave = 16 output rows x (NT*16) cols, accumulate over 27 offsets in AGPRs.
// All 27 tab entries preloaded (independent loads, one latency); k-loop fully
// unrolled so idx[] stays in registers (static indexing) and the scheduler can
// hoist A-gathers across iterations. SKIP=false for dense stages (SubM conv).
template<int KK, int NT, bool SKIP>
__global__ __launch_bounds__(256) void conv_mfma_kernel(
    const unsigned short* __restrict__ Xb, const unsigned short* __restrict__ Wp,
    const int* __restrict__ tab, int maxo, int zrow,
    const int* __restrict__ n_ptr, int n_cap,
    unsigned short* __restrict__ outb, float* __restrict__ outf) {
  const int CO = NT * 16;
  const int ROWS = KK * 32;  // shorts per X row
  int wid = threadIdx.x >> 6, l = threadIdx.x & 63;
  int obase = (blockIdx.x * 4 + wid) * 16;
  int n_rows = n_cap;
  if (n_ptr) { int nv = n_ptr[0]; if (nv < n_rows) n_rows = nv; }
  if (obase >= n_rows) return;
  int lr = l & 15, lg = l >> 4;
  int o = obase + lr;
  bool orow_ok = (o < n_rows);

  int idx[27];
#pragma unroll
  for (int k = 0; k < 27; ++k)
    idx[k] = orow_ok ? tab[(size_t)k * maxo + o] : -1;

  f32x4 acc[NT] = {};

#pragma unroll
  for (int k = 0; k < 27; ++k) {
    if (SKIP) {
      if (__ballot(idx[k] >= 0) == 0ull) continue;  // no valid pair in any of the 16 rows
    }
    size_t abase = (size_t)(idx[k] < 0 ? zrow : idx[k]) * ROWS + lg * 8;
#pragma unroll
    for (int kk = 0; kk < KK; ++kk) {
      bf16x8 a = *reinterpret_cast<const bf16x8*>(Xb + abase + kk * 32);
#pragma unroll
      for (int nt = 0; nt < NT; ++nt) {
        bf16x8 b = *reinterpret_cast<const bf16x8*>(
            Wp + ((((size_t)k * NT + nt) * KK + kk) << 9) + l * 8);
        acc[nt] = __builtin_amdgcn_mfma_f32_16x16x32_bf16(a, b, acc[nt], 0, 0, 0);
      }
    }
  }

  int orow0 = obase + lg * 4;
#pragma unroll
  for (int nt = 0; nt < NT; ++nt) {
#pragma unroll
    for (int r = 0; r < 4; ++r) {
      int orow = orow0 + r;
      if (orow < n_rows) {
        size_t off = (size_t)orow * CO + nt * 16 + lr;
        if (outf) outf[off] = acc[nt][r];
        else outb[off] = f2bf(acc[nt][r]);
      }
    }
  }
}

// BN stats: lane = (row%4, 4-channel group), uint2 (4 bf16) per load.
__global__ void bn_stats_kernel(const unsigned short* __restrict__ xb,
                                const int* __restrict__ n_ptr, int n_cap,
                                float* __restrict__ stats) {
  int n = n_ptr[0]; if (n > n_cap) n = n_cap;
  int t = threadIdx.x;
  int l = t & 63, w = t >> 6;
  int rl = l >> 4, cg = (l & 15) * 4;
  float s0=0,s1=0,s2=0,s3=0,q0=0,q1=0,q2=0,q3=0;
  for (int r = blockIdx.x * 16 + w * 4 + rl; r < n; r += gridDim.x * 16) {
    uint2 d = *reinterpret_cast<const uint2*>(xb + (size_t)r * 64 + cg);
    float v0 = bf2f(d.x & 0xffffu), v1 = bf2f(d.x >> 16);
    float v2 = bf2f(d.y & 0xffffu), v3 = bf2f(d.y >> 16);
    s0 += v0; q0 += v0 * v0; s1 += v1; q1 += v1 * v1;
    s2 += v2; q2 += v2 * v2; s3 += v3; q3 += v3 * v3;
  }
#pragma unroll
  for (int m = 16; m <= 32; m <<= 1) {
    s0 += __shfl_xor(s0, m); s1 += __shfl_xor(s1, m);
    s2 += __shfl_xor(s2, m); s3 += __shfl_xor(s3, m);
    q0 += __shfl_xor(q0, m); q1 += __shfl_xor(q1, m);
    q2 += __shfl_xor(q2, m); q3 += __shfl_xor(q3, m);
  }
  if (rl == 0) {
    atomicAdd(&stats[cg + 0], s0); atomicAdd(&stats[cg + 1], s1);
    atomicAdd(&stats[cg + 2], s2); atomicAdd(&stats[cg + 3], s3);
    atomicAdd(&stats[64 + cg + 0], q0); atomicAdd(&stats[64 + cg + 1], q1);
    atomicAdd(&stats[64 + cg + 2], q2); atomicAdd(&stats[64 + cg + 3], q3);
  }
}

__global__ void bn_apply_kernel(unsigned short* __restrict__ xb,
                                const int* __restrict__ n_ptr, int n_cap,
                                const float* __restrict__ stats,
                                const float* __restrict__ gamma,
                                const float* __restrict__ beta) {
  int n = n_ptr[0]; if (n > n_cap) n = n_cap;
  int t = blockIdx.x * 256 + threadIdx.x;
  int cg = (t & 15) * 4;
  float inv_n = 1.f / (float)n;
  float sc[4], sh[4];
#pragma unroll
  for (int i = 0; i < 4; ++i) {
    float m = stats[cg + i] * inv_n;
    float var = stats[64 + cg + i] * inv_n - m * m;
    float s = gamma[cg + i] * rsqrtf(var + 1e-5f);
    sc[i] = s; sh[i] = beta[cg + i] - m * s;
  }
  int rstep = (gridDim.x * 256) >> 4;
  for (int r = t >> 4; r < n; r += rstep) {
    size_t off = (size_t)r * 64 + cg;
    uint2 d = *reinterpret_cast<uint2*>(xb + off);
    float v0 = bf2f(d.x & 0xffffu) * sc[0] + sh[0]; if (v0 < 0.f) v0 = 0.f;
    float v1 = bf2f(d.x >> 16)     * sc[1] + sh[1]; if (v1 < 0.f) v1 = 0.f;
    float v2 = bf2f(d.y & 0xffffu) * sc[2] + sh[2]; if (v2 < 0.f) v2 = 0.f;
    float v3 = bf2f(d.y >> 16)     * sc[3] + sh[3]; if (v3 < 0.f) v3 = 0.f;
    d.x = (unsigned int)f2bf(v0) | ((unsigned int)f2bf(v1) << 16);
    d.y = (unsigned int)f2bf(v2) | ((unsigned int)f2bf(v3) << 16);
    *reinterpret_cast<uint2*>(xb + off) = d;
  }
}

extern "C" void kernel_launch(void* const* d_in, const int* in_sizes, int n_in,
                              void* d_out, int out_size, void* d_ws, size_t ws_size,
                              hipStream_t stream) {
  const float* feats  = (const float*)d_in[0];
  const float* W1     = (const float*)d_in[1];
  const float* g1     = (const float*)d_in[2];
  const float* b1     = (const float*)d_in[3];
  const float* W2     = (const float*)d_in[4];
  const float* g2     = (const float*)d_in[5];
  const float* b2     = (const float*)d_in[6];
  const float* W3     = (const float*)d_in[7];
  const int* p1_in    = (const int*)d_in[8];
  const int* p1_out   = (const int*)d_in[9];
  const int* p2_in    = (const int*)d_in[10];
  const int* p2_out   = (const int*)d_in[11];
  const int* d_n1     = (const int*)d_in[12];
  float* out = (float*)d_out;

  const int N  = in_sizes[0] / 16;     // 200000
  const int P1 = in_sizes[8] / 27;
  const int P2 = in_sizes[10] / 27;
  long KP1 = in_sizes[8];
  int n1b = (int)(KP1 < 980100 ? KP1 : 980100);   // n1 <= min(#pairs1, out-grid size 2*99*99*50)
  int maxo = n1b > N ? n1b : N;

  char* p = (char*)d_ws;
  auto alloc = [&](size_t bytes) -> char* {
    char* r = p; p += (bytes + 255) & ~(size_t)255; return r;
  };
  unsigned short* featsb = (unsigned short*)alloc((size_t)(N + 1) * 32 * 2);
  unsigned short* x1b    = (unsigned short*)alloc((size_t)(n1b + 1) * 64 * 2);
  unsigned short* x2b    = (unsigned short*)alloc((size_t)(n1b + 1) * 64 * 2);
  unsigned short* W1p    = (unsigned short*)alloc((size_t)27 * 4 * 1 * 512 * 2);
  unsigned short* W2p    = (unsigned short*)alloc((size_t)27 * 4 * 2 * 512 * 2);
  unsigned short* W3p    = (unsigned short*)alloc((size_t)27 * 2 * 2 * 512 * 2);
  int*   tab   = (int*)alloc((size_t)maxo * 27 * 4);
  float* stats = (float*)alloc(256 * 4);
  if ((size_t)(p - (char*)d_ws) > ws_size) return;  // workspace insufficient -> fail visibly

  // zero-init: padded feats buffer, the two zero-rows, BN stats
  hipMemsetAsync(featsb, 0, (size_t)(N + 1) * 32 * 2, stream);
  hipMemsetAsync(x1b + (size_t)n1b * 64, 0, 64 * 2, stream);
  hipMemsetAsync(x2b + (size_t)n1b * 64, 0, 64 * 2, stream);
  hipMemsetAsync(stats, 0, 256 * 4, stream);

  cvt_feats_kernel<<<(N * 16 + 255) / 256, 256, 0, stream>>>(feats, featsb, N * 16);
  pack_w_kernel<<<(27 * 4 * 1 * 512 + 255) / 256, 256, 0, stream>>>(W1, W1p, 16, 64, 4, 1);
  pack_w_kernel<<<(27 * 4 * 2 * 512 + 255) / 256, 256, 0, stream>>>(W2, W2p, 64, 64, 4, 2);
  pack_w_kernel<<<(27 * 2 * 2 * 512 + 255) / 256, 256, 0, stream>>>(W3, W3p, 64, 32, 2, 2);

  // ---- stage 1: SparseConv3d 16->64 (sparse pairs -> SKIP=true) ----
  fill_tab_kernel<<<dim3((n1b + 255) / 256, 27), 256, 0, stream>>>(tab, n1b, d_n1, n1b);
  build_table_kernel<<<dim3((P1 + 255) / 256, 27), 256, 0, stream>>>(
      p1_in, p1_out, P1, n1b, tab, d_n1, n1b);
  conv_mfma_kernel<1, 4, true><<<(n1b + 63) / 64, 256, 0, stream>>>(
      featsb, W1p, tab, n1b, N, d_n1, n1b, x1b, nullptr);
  bn_stats_kernel<<<512, 256, 0, stream>>>(x1b, d_n1, n1b, stats);
  bn_apply_kernel<<<2048, 256, 0, stream>>>(x1b, d_n1, n1b, stats, g1, b1);

  // ---- stage 2: SubMConv3d 64->64 (dense pairs -> SKIP=false, straight-line) ----
  fill_tab_kernel<<<dim3((n1b + 255) / 256, 27), 256, 0, stream>>>(tab, n1b, d_n1, n1b);
  build_table_kernel<<<dim3((P2 + 255) / 256, 27), 256, 0, stream>>>(
      p2_in, p2_out, P2, n1b, tab, d_n1, n1b);
  conv_mfma_kernel<2, 4, false><<<(n1b + 63) / 64, 256, 0, stream>>>(
      x1b, W2p, tab, n1b, n1b, d_n1, n1b, x2b, nullptr);
  bn_stats_kernel<<<512, 256, 0, stream>>>(x2b, d_n1, n1b, stats + 128);
  bn_apply_kernel<<<2048, 256, 0, stream>>>(x2b, d_n1, n1b, stats + 128, g2, b2);

  // ---- stage 3: SparseInverseConv3d 64->32 (pairs swapped, sparse -> SKIP=true) ----
  fill_tab_kernel<<<dim3((N + 255) / 256, 27), 256, 0, stream>>>(tab, N, nullptr, N);
  build_table_kernel<<<dim3((P1 + 255) / 256, 27), 256, 0, stream>>>(
      p1_out, p1_in, P1, N, tab, nullptr, N);
  conv_mfma_kernel<2, 2, true><<<(N + 63) / 64, 256, 0, stream>>>(
      x2b, W3p, tab, N, n1b, nullptr, N, nullptr, out);
}

// Round 3
// 710.392 us; speedup vs baseline: 1.5309x; 1.5309x over previous
//
#include <hip/hip_runtime.h>
#include <hip/hip_bf16.h>

typedef __bf16 bf16x8 __attribute__((ext_vector_type(8)));
typedef float f32x4 __attribute__((ext_vector_type(4)));

__device__ __forceinline__ unsigned short f2bf(float x) {
  union { float f; unsigned int u; } v; v.f = x;
  unsigned int r = (v.u + 0x7FFFu + ((v.u >> 16) & 1u)) >> 16;
  return (unsigned short)r;
}
__device__ __forceinline__ float bf2f(unsigned short u) {
  union { unsigned int u; float f; } v; v.u = ((unsigned int)u) << 16;
  return v.f;
}

// feats [N][16] f32 -> [N+1][32] bf16 (upper 16 cols and row N stay zero via memset)
__global__ void cvt_feats_kernel(const float* __restrict__ f, unsigned short* __restrict__ fb, int n16) {
  int t = blockIdx.x * 256 + threadIdx.x;
  if (t >= n16) return;
  int i = t >> 4, j = t & 15;
  fb[(size_t)i * 32 + j] = f2bf(f[t]);
}

// Pack W[k][CI][CO] f32 into MFMA B-fragment order:
// Wp[(((k*NT+nt)*KK+kk)*64 + l)*8 + j] = bf16(W[k][kk*32 + (l>>4)*8 + j][nt*16 + (l&15)]), 0 if kg>=CI
__global__ void pack_w_kernel(const float* __restrict__ W, unsigned short* __restrict__ Wp,
                              int CI, int CO, int NT, int KK) {
  int t = blockIdx.x * 256 + threadIdx.x;
  int total = 27 * NT * KK * 512;
  if (t >= total) return;
  int j = t & 7, l = (t >> 3) & 63;
  int g = t >> 9;
  int kk = g % KK; g /= KK;
  int nt = g % NT; int k = g / NT;
  int kg = kk * 32 + ((l >> 4) * 8) + j;
  int c = nt * 16 + (l & 15);
  float v = (kg < CI) ? W[((size_t)k * CI + kg) * CO + c] : 0.0f;
  Wp[t] = f2bf(v);
}

// tab[k][o] = input index (scatter from pair lists; unique per (k,o) by construction)
__global__ void build_table_kernel(const int* __restrict__ pin, const int* __restrict__ pout,
                                   int P, int maxo, int* __restrict__ tab,
                                   const int* __restrict__ n_ptr, int n_cap) {
  int p = blockIdx.x * 256 + threadIdx.x;
  if (p >= P) return;
  int k = blockIdx.y;
  int n = n_cap;
  if (n_ptr) { int nv = n_ptr[0]; if (nv < n) n = nv; }
  size_t e = (size_t)k * P + p;
  int o = pout[e];
  if (o < n) tab[(size_t)k * maxo + o] = pin[e];
}

// One software-pipeline step: prefetch A(k+1)/B(k+1) into (AN,BN) + tab(k+2),
// then 32 (MT*NT*KK) MFMAs on (AC,BC). All array indexing compile-time static.
#define CONV_STEP(K, AC, BC, AN, BN) do {                                        \
    int kp1 = (K) + 1 < 27 ? (K) + 1 : 26;                                       \
    int kp2 = (K) + 2 < 27 ? (K) + 2 : 26;                                       \
    _Pragma("unroll") for (int mt = 0; mt < MT; ++mt) {                          \
      int ri = __shfl(iB, mt * 16 + lr);                                         \
      const unsigned short* src = Xb + (size_t)(ri < 0 ? zrow : ri) * ROWS + lg * 8; \
      _Pragma("unroll") for (int kk = 0; kk < KK; ++kk)                          \
        AN[mt][kk] = *reinterpret_cast<const bf16x8*>(src + kk * 32);            \
    }                                                                            \
    _Pragma("unroll") for (int nt = 0; nt < NT; ++nt)                            \
      _Pragma("unroll") for (int kk = 0; kk < KK; ++kk)                          \
        BN[nt][kk] = *reinterpret_cast<const bf16x8*>(                           \
            Wp + ((((size_t)kp1 * NT + nt) * KK + kk) << 9) + l * 8);            \
    int iN = ok ? tab[(size_t)kp2 * maxo + ro] : -1;                             \
    _Pragma("unroll") for (int kk = 0; kk < KK; ++kk)                            \
      _Pragma("unroll") for (int mt = 0; mt < MT; ++mt)                          \
        _Pragma("unroll") for (int nt = 0; nt < NT; ++nt)                        \
          acc[mt][nt] = __builtin_amdgcn_mfma_f32_16x16x32_bf16(                 \
              AC[mt][kk], BC[nt][kk], acc[mt][nt], 0, 0, 0);                     \
    iB = iN;                                                                     \
  } while (0)

// One wave = MT*16 output rows x (NT*16) cols. B-fragments amortized over MT
// row-groups; 1-deep ping-pong pipeline; coalesced tab load (1 per k) with
// __shfl distribution; bijective XCD swizzle for gather L2 locality.
template<int KK, int NT, int MT>
__global__ __launch_bounds__(256, 2) void conv_mfma_kernel(
    const unsigned short* __restrict__ Xb, const unsigned short* __restrict__ Wp,
    const int* __restrict__ tab, int maxo, int zrow,
    const int* __restrict__ n_ptr, int n_cap,
    unsigned short* __restrict__ outb, float* __restrict__ outf) {
  const int CO = NT * 16;
  const int ROWS = KK * 32;     // shorts per X row
  const int RPW = 16 * MT;      // output rows per wave

  int bid = blockIdx.x;
  { // bijective XCD-aware swizzle (m204)
    int nwg = gridDim.x;
    int q = nwg >> 3, r = nwg & 7;
    int xcd = bid & 7, orig = bid >> 3;
    bid = (xcd < r ? xcd * (q + 1) : r * (q + 1) + (xcd - r) * q) + orig;
  }

  int wid = threadIdx.x >> 6, l = threadIdx.x & 63;
  int n_rows = n_cap;
  if (n_ptr) { int nv = n_ptr[0]; if (nv < n_rows) n_rows = nv; }
  int wbase = (bid * 4 + wid) * RPW;
  if (wbase >= n_rows) return;
  int lr = l & 15, lg = l >> 4;
  int ro = wbase + (l & (RPW - 1));
  bool ok = (ro < n_rows);

  f32x4 acc[MT][NT] = {};
  bf16x8 aC[MT][KK], aN[MT][KK], bC[NT][KK], bN[NT][KK];

  // prologue: idx(0) -> gather A(0); B(0); idx(1)
  int iB = ok ? tab[ro] : -1;
#pragma unroll
  for (int mt = 0; mt < MT; ++mt) {
    int ri = __shfl(iB, mt * 16 + lr);
    const unsigned short* src = Xb + (size_t)(ri < 0 ? zrow : ri) * ROWS + lg * 8;
#pragma unroll
    for (int kk = 0; kk < KK; ++kk)
      aC[mt][kk] = *reinterpret_cast<const bf16x8*>(src + kk * 32);
  }
#pragma unroll
  for (int nt = 0; nt < NT; ++nt)
#pragma unroll
    for (int kk = 0; kk < KK; ++kk)
      bC[nt][kk] = *reinterpret_cast<const bf16x8*>(Wp + (((size_t)(nt * KK + kk)) << 9) + l * 8);
  iB = ok ? tab[(size_t)maxo + ro] : -1;

#pragma unroll 1
  for (int k = 0; k < 26; k += 2) {
    CONV_STEP(k,     aC, bC, aN, bN);
    CONV_STEP(k + 1, aN, bN, aC, bC);
  }
  // epilogue: k = 26 (data sits in aC/bC)
#pragma unroll
  for (int kk = 0; kk < KK; ++kk)
#pragma unroll
    for (int mt = 0; mt < MT; ++mt)
#pragma unroll
      for (int nt = 0; nt < NT; ++nt)
        acc[mt][nt] = __builtin_amdgcn_mfma_f32_16x16x32_bf16(
            aC[mt][kk], bC[nt][kk], acc[mt][nt], 0, 0, 0);

#pragma unroll
  for (int mt = 0; mt < MT; ++mt) {
    int r0 = wbase + mt * 16 + lg * 4;
#pragma unroll
    for (int rr = 0; rr < 4; ++rr) {
      int row = r0 + rr;
      if (row < n_rows) {
#pragma unroll
        for (int nt = 0; nt < NT; ++nt) {
          size_t off = (size_t)row * CO + nt * 16 + lr;
          if (outf) outf[off] = acc[mt][nt][rr];
          else outb[off] = f2bf(acc[mt][nt][rr]);
        }
      }
    }
  }
}

__global__ void bn_stats_kernel(const unsigned short* __restrict__ xb,
                                const int* __restrict__ n_ptr, int n_cap,
                                float* __restrict__ stats) {
  int c = threadIdx.x & 63, q = threadIdx.x >> 6;
  int n = n_ptr[0]; if (n > n_cap) n = n_cap;
  float s = 0.f, ss = 0.f;
  for (int r = blockIdx.x * 4 + q; r < n; r += gridDim.x * 4) {
    float v = bf2f(xb[(size_t)r * 64 + c]);
    s += v; ss += v * v;
  }
  __shared__ float ls[8][64];
  ls[q][c] = s; ls[4 + q][c] = ss;
  __syncthreads();
  if (q == 0) {
    s = ls[0][c] + ls[1][c] + ls[2][c] + ls[3][c];
    ss = ls[4][c] + ls[5][c] + ls[6][c] + ls[7][c];
    atomicAdd(&stats[c], s);
    atomicAdd(&stats[64 + c], ss);
  }
}

__global__ void bn_apply_kernel(unsigned short* __restrict__ xb,
                                const int* __restrict__ n_ptr, int n_cap,
                                const float* __restrict__ stats,
                                const float* __restrict__ gamma, const float* __restrict__ beta) {
  int c = threadIdx.x & 63, q = threadIdx.x >> 6;
  int n = n_ptr[0]; if (n > n_cap) n = n_cap;
  float inv_n = 1.f / (float)n;
  float m = stats[c] * inv_n;
  float var = stats[64 + c] * inv_n - m * m;
  float sc = gamma[c] * rsqrtf(var + 1e-5f);
  float sh = beta[c] - m * sc;
  for (int r = blockIdx.x * 4 + q; r < n; r += gridDim.x * 4) {
    size_t off = (size_t)r * 64 + c;
    float v = bf2f(xb[off]) * sc + sh;
    xb[off] = f2bf(v > 0.f ? v : 0.f);
  }
}

extern "C" void kernel_launch(void* const* d_in, const int* in_sizes, int n_in,
                              void* d_out, int out_size, void* d_ws, size_t ws_size,
                              hipStream_t stream) {
  const float* feats  = (const float*)d_in[0];
  const float* W1     = (const float*)d_in[1];
  const float* g1     = (const float*)d_in[2];
  const float* b1     = (const float*)d_in[3];
  const float* W2     = (const float*)d_in[4];
  const float* g2     = (const float*)d_in[5];
  const float* b2     = (const float*)d_in[6];
  const float* W3     = (const float*)d_in[7];
  const int* p1_in    = (const int*)d_in[8];
  const int* p1_out   = (const int*)d_in[9];
  const int* p2_in    = (const int*)d_in[10];
  const int* p2_out   = (const int*)d_in[11];
  const int* d_n1     = (const int*)d_in[12];
  float* out = (float*)d_out;

  const int N  = in_sizes[0] / 16;     // 200000
  const int P1 = in_sizes[8] / 27;
  const int P2 = in_sizes[10] / 27;
  long KP1 = in_sizes[8];
  int n1b = (int)(KP1 < 980100 ? KP1 : 980100);   // n1 <= min(#pairs1, out-grid size 2*99*99*50)
  int maxo = n1b > N ? n1b : N;

  char* p = (char*)d_ws;
  auto alloc = [&](size_t bytes) -> char* {
    char* r = p; p += (bytes + 255) & ~(size_t)255; return r;
  };
  unsigned short* featsb = (unsigned short*)alloc((size_t)(N + 1) * 32 * 2);
  unsigned short* x1b    = (unsigned short*)alloc((size_t)(n1b + 1) * 64 * 2);
  unsigned short* x2b    = (unsigned short*)alloc((size_t)(n1b + 1) * 64 * 2);
  unsigned short* W1p    = (unsigned short*)alloc((size_t)27 * 4 * 1 * 512 * 2);
  unsigned short* W2p    = (unsigned short*)alloc((size_t)27 * 4 * 2 * 512 * 2);
  unsigned short* W3p    = (unsigned short*)alloc((size_t)27 * 2 * 2 * 512 * 2);
  int*   tab   = (int*)alloc((size_t)maxo * 27 * 4);
  float* stats = (float*)alloc(256 * 4);
  if ((size_t)(p - (char*)d_ws) > ws_size) return;  // workspace insufficient -> fail visibly

  // zero-init: padded feats buffer, the two zero-rows, BN stats
  hipMemsetAsync(featsb, 0, (size_t)(N + 1) * 32 * 2, stream);
  hipMemsetAsync(x1b + (size_t)n1b * 64, 0, 64 * 2, stream);
  hipMemsetAsync(x2b + (size_t)n1b * 64, 0, 64 * 2, stream);
  hipMemsetAsync(stats, 0, 256 * 4, stream);

  cvt_feats_kernel<<<(N * 16 + 255) / 256, 256, 0, stream>>>(feats, featsb, N * 16);
  pack_w_kernel<<<(27 * 4 * 1 * 512 + 255) / 256, 256, 0, stream>>>(W1, W1p, 16, 64, 4, 1);
  pack_w_kernel<<<(27 * 4 * 2 * 512 + 255) / 256, 256, 0, stream>>>(W2, W2p, 64, 64, 4, 2);
  pack_w_kernel<<<(27 * 2 * 2 * 512 + 255) / 256, 256, 0, stream>>>(W3, W3p, 64, 32, 2, 2);

  // ---- stage 1: SparseConv3d 16->64 ----
  hipMemsetAsync(tab, 0xFF, (size_t)n1b * 27 * 4, stream);
  build_table_kernel<<<dim3((P1 + 255) / 256, 27), 256, 0, stream>>>(
      p1_in, p1_out, P1, n1b, tab, d_n1, n1b);
  conv_mfma_kernel<1, 4, 4><<<(n1b + 255) / 256, 256, 0, stream>>>(
      featsb, W1p, tab, n1b, N, d_n1, n1b, x1b, nullptr);
  bn_stats_kernel<<<1024, 256, 0, stream>>>(x1b, d_n1, n1b, stats);
  bn_apply_kernel<<<2048, 256, 0, stream>>>(x1b, d_n1, n1b, stats, g1, b1);

  // ---- stage 2: SubMConv3d 64->64 ----
  hipMemsetAsync(tab, 0xFF, (size_t)n1b * 27 * 4, stream);
  build_table_kernel<<<dim3((P2 + 255) / 256, 27), 256, 0, stream>>>(
      p2_in, p2_out, P2, n1b, tab, d_n1, n1b);
  conv_mfma_kernel<2, 4, 4><<<(n1b + 255) / 256, 256, 0, stream>>>(
      x1b, W2p, tab, n1b, n1b, d_n1, n1b, x2b, nullptr);
  bn_stats_kernel<<<1024, 256, 0, stream>>>(x2b, d_n1, n1b, stats + 128);
  bn_apply_kernel<<<2048, 256, 0, stream>>>(x2b, d_n1, n1b, stats + 128, g2, b2);

  // ---- stage 3: SparseInverseConv3d 64->32 (pairs swapped) ----
  hipMemsetAsync(tab, 0xFF, (size_t)N * 27 * 4, stream);
  build_table_kernel<<<dim3((P1 + 255) / 256, 27), 256, 0, stream>>>(
      p1_out, p1_in, P1, N, tab, nullptr, N);
  conv_mfma_kernel<2, 2, 4><<<(N + 255) / 256, 256, 0, stream>>>(
      x2b, W3p, tab, N, n1b, nullptr, N, nullptr, out);
}